// Round 9
// baseline (57.384 us; speedup 1.0000x reference)
//
#include <hip/hip_runtime.h>

// CRF NLL forward — INSTRUMENTED ROUND (R9): the verified R8 tree kernel with
// the full computation executed TWICE per wave (identical result written both
// times). Purpose: surface crf_tree in rocprof top-5 (it was masked by the
// harness's 57us fill kernels) and measure true kernel time as
// dur(R9) - dur(R8). Compute structure is bit-identical to R8 otherwise.

#define BB 8192
#define LL 512
#define LN2F 0.69314718055994530942f

__device__ __forceinline__ float uniformf(float x) {
    return __uint_as_float(__builtin_amdgcn_readfirstlane(__float_as_uint(x)));
}

#define RENORM16(P, MEX)                                                \
  do {                                                                  \
    float m_ = fmaxf(P[0], P[1]);                                       \
    _Pragma("unroll") for (int z_ = 2; z_ < 16; ++z_) m_ = fmaxf(m_, P[z_]); \
    const int ee_ = (int)((__float_as_uint(m_) >> 23) & 255) - 127;     \
    const float sc_ = __uint_as_float((unsigned)(127 - ee_) << 23);     \
    _Pragma("unroll") for (int z_ = 0; z_ < 16; ++z_) P[z_] *= sc_;     \
    MEX += ee_;                                                         \
  } while (0)

// One leaf step for r>=1: P <- diag(exp(f)) * E * P (masked), fused gold.
#define STEP(R, F0, F1, F2, F3)                                         \
  do {                                                                  \
    const bool act_ = (base + (R)) < len;                               \
    const float f0_=(F0), f1_=(F1), f2_=(F2), f3_=(F3);                 \
    const float fe0_=__expf(f0_), fe1_=__expf(f1_);                     \
    const float fe2_=__expf(f2_), fe3_=__expf(f3_);                     \
    _Pragma("unroll")                                                   \
    for (int j = 0; j < 4; ++j) {                                       \
      const float c0_=P[0*4+j], c1_=P[1*4+j], c2_=P[2*4+j], c3_=P[3*4+j]; \
      const float t0_ = fmaf(E[0], c0_, fmaf(E[1], c1_, fmaf(E[2], c2_, E[3] *c3_))); \
      const float t1_ = fmaf(E[4], c0_, fmaf(E[5], c1_, fmaf(E[6], c2_, E[7] *c3_))); \
      const float t2_ = fmaf(E[8], c0_, fmaf(E[9], c1_, fmaf(E[10],c2_, E[11]*c3_))); \
      const float t3_ = fmaf(E[12],c0_, fmaf(E[13],c1_, fmaf(E[14],c2_, E[15]*c3_))); \
      P[0*4+j] = act_ ? fe0_*t0_ : P[0*4+j];                            \
      P[1*4+j] = act_ ? fe1_*t1_ : P[1*4+j];                            \
      P[2*4+j] = act_ ? fe2_*t2_ : P[2*4+j];                            \
      P[3*4+j] = act_ ? fe3_*t3_ : P[3*4+j];                            \
    }                                                                   \
    const int tg_ = tg##R;                                              \
    const float lut_ = sT[tg_ * 6 + tgp##R];                            \
    const float em_  = (tg_ & 2) ? ((tg_ & 1) ? f3_ : f2_)              \
                                 : ((tg_ & 1) ? f1_ : f0_);             \
    gold += act_ ? (lut_ + em_) : 0.f;                                  \
  } while (0)

__global__ __launch_bounds__(256, 4) void crf_tree(
    const float* __restrict__ feats,
    const float* __restrict__ trans,
    const int*   __restrict__ tags,
    const int*   __restrict__ lens,
    float* __restrict__ partials)
{
    __shared__ float sT[36];

    const int tid  = threadIdx.x;
    const int lane = tid & 63;
    const int wv   = tid >> 6;
    const int b    = blockIdx.x * 4 + wv;

    if (tid < 36) sT[tid] = trans[tid];
    __syncthreads();

    // wave-uniform transition constants (SGPR via readfirstlane)
    float E[16], e4[4], e5[4];
    #pragma unroll
    for (int i = 0; i < 16; ++i)
        E[i] = uniformf(__expf(sT[(i >> 2) * 6 + (i & 3)]));
    #pragma unroll
    for (int i = 0; i < 4; ++i) {
        e4[i] = uniformf(__expf(sT[i * 6 + 4]));   // exp(trans[i][START])
        e5[i] = uniformf(__expf(sT[30 + i]));      // exp(trans[STOP][i])
    }

    const int len  = lens[b];
    const int base = lane * 8;
    const bool lane0 = (lane == 0);
    const float* fp = feats + (size_t)b * (LL * 6) + lane * 48;
    const int* tbp = tags + (size_t)b * LL + base;

    // ======== INSTRUMENTATION: run the identical computation twice ========
    #pragma unroll 1
    for (int rep_ = 0; rep_ < 2; ++rep_) {
        asm volatile("" ::: "memory");   // force real re-loads each rep

        const float4 A0 = *(const float4*)(fp + 0);    // step 0: f0..f3
        const float2 A1 = *(const float2*)(fp + 6);    // step 1: f0,f1
        const float2 A2 = *(const float2*)(fp + 8);    // step 1: f2,f3
        const float4 B0 = *(const float4*)(fp + 12);   // step 2
        const float2 B1 = *(const float2*)(fp + 18);   // step 3
        const float2 B2 = *(const float2*)(fp + 20);
        const float4 C0 = *(const float4*)(fp + 24);   // step 4
        const float2 C1 = *(const float2*)(fp + 30);   // step 5
        const float2 C2 = *(const float2*)(fp + 32);
        const float4 D0 = *(const float4*)(fp + 36);   // step 6
        const float2 D1 = *(const float2*)(fp + 42);   // step 7
        const float2 D2 = *(const float2*)(fp + 44);

        const int4 ta  = *(const int4*)tbp;
        const int4 tb4 = *(const int4*)(tbp + 4);
        const int tg0=ta.x&3,  tg1=ta.y&3,  tg2=ta.z&3,  tg3=ta.w&3;
        const int tg4=tb4.x&3, tg5=tb4.y&3, tg6=tb4.z&3, tg7=tb4.w&3;
        const int ptail = __shfl_up(tg7, 1, 64);
        const int prev0 = lane0 ? 4 : ptail;
        const int tgp1=tg0, tgp2=tg1, tgp3=tg2,
                  tgp4=tg3, tgp5=tg4, tgp6=tg5, tgp7=tg6;

        float P[16];
        #pragma unroll
        for (int z = 0; z < 16; ++z) P[z] = (z % 5 == 0) ? 1.f : 0.f;
        int   mex  = 0;
        float gold = 0.f;

        // step 0 specialized: P = diag(fe) * (lane0 ? e4-cols : E)
        {
            const bool act_ = base < len;
            const float f0_=A0.x, f1_=A0.y, f2_=A0.z, f3_=A0.w;
            const float fe0_=__expf(f0_), fe1_=__expf(f1_);
            const float fe2_=__expf(f2_), fe3_=__expf(f3_);
            #pragma unroll
            for (int j = 0; j < 4; ++j) {
                const float t0_ = lane0 ? e4[0] : E[0*4+j];
                const float t1_ = lane0 ? e4[1] : E[1*4+j];
                const float t2_ = lane0 ? e4[2] : E[2*4+j];
                const float t3_ = lane0 ? e4[3] : E[3*4+j];
                P[0*4+j] = act_ ? fe0_*t0_ : P[0*4+j];
                P[1*4+j] = act_ ? fe1_*t1_ : P[1*4+j];
                P[2*4+j] = act_ ? fe2_*t2_ : P[2*4+j];
                P[3*4+j] = act_ ? fe3_*t3_ : P[3*4+j];
            }
            const float lut_ = sT[tg0 * 6 + prev0];
            const float em_  = (tg0 & 2) ? ((tg0 & 1) ? f3_ : f2_)
                                         : ((tg0 & 1) ? f1_ : f0_);
            gold += act_ ? (lut_ + em_) : 0.f;
        }
        STEP(1, A1.x, A1.y, A2.x, A2.y);
        STEP(2, B0.x, B0.y, B0.z, B0.w);
        STEP(3, B1.x, B1.y, B2.x, B2.y);
        RENORM16(P, mex);
        STEP(4, C0.x, C0.y, C0.z, C0.w);
        STEP(5, C1.x, C1.y, C2.x, C2.y);
        STEP(6, D0.x, D0.y, D0.z, D0.w);
        STEP(7, D1.x, D1.y, D2.x, D2.y);
        RENORM16(P, mex);

        // terminal gold
        {
            const unsigned dl = (unsigned)(len - 1 - base);
            if (dl < 8u) gold += sT[30 + (tbp[dl] & 3)];
        }

        // butterfly rounds k=1..16 (full 4x4 products)
        #pragma unroll
        for (int k = 1; k <= 16; k <<= 1) {
            float Q[16];
            #pragma unroll
            for (int z = 0; z < 16; ++z) Q[z] = __shfl_xor(P[z], k, 64);
            const int mq = __shfl_xor(mex, k, 64);
            const bool lat = (lane & k) != 0;
            float A[16], Bm[16];
            #pragma unroll
            for (int z = 0; z < 16; ++z) {
                A[z]  = lat ? P[z] : Q[z];
                Bm[z] = lat ? Q[z] : P[z];
            }
            #pragma unroll
            for (int i = 0; i < 4; ++i)
                #pragma unroll
                for (int j = 0; j < 4; ++j)
                    P[i*4+j] = fmaf(A[i*4+0], Bm[0*4+j], fmaf(A[i*4+1], Bm[1*4+j],
                               fmaf(A[i*4+2], Bm[2*4+j], A[i*4+3] * Bm[3*4+j])));
            mex += mq;
            RENORM16(P, mex);
        }

        // final round k=32: earlier half rank-1 -> mat-vec only
        float al0, al1, al2, al3;
        {
            float Q[16];
            #pragma unroll
            for (int z = 0; z < 16; ++z) Q[z] = __shfl_xor(P[z], 32, 64);
            const int mq = __shfl_xor(mex, 32, 64);
            const bool lat = (lane & 32) != 0;
            const float b0 = lat ? Q[0]  : P[0];
            const float b1 = lat ? Q[4]  : P[4];
            const float b2 = lat ? Q[8]  : P[8];
            const float b3 = lat ? Q[12] : P[12];
            #pragma unroll
            for (int i = 0; i < 4; ++i) {
                const float a0 = lat ? P[i*4+0] : Q[i*4+0];
                const float a1 = lat ? P[i*4+1] : Q[i*4+1];
                const float a2 = lat ? P[i*4+2] : Q[i*4+2];
                const float a3 = lat ? P[i*4+3] : Q[i*4+3];
                const float v = fmaf(a0, b0, fmaf(a1, b1, fmaf(a2, b2, a3 * b3)));
                if (i == 0) al0 = v; else if (i == 1) al1 = v;
                else if (i == 2) al2 = v; else al3 = v;
            }
            mex += mq;
        }

        // gold: sum across lanes
        #pragma unroll
        for (int k = 1; k <= 32; k <<= 1)
            gold += __shfl_xor(gold, k, 64);

        const float dot = fmaf(e5[0], al0, fmaf(e5[1], al1,
                          fmaf(e5[2], al2, e5[3] * al3)));
        const float logz = fmaf((float)mex, LN2F, __logf(dot));
        if (lane == 0)
            partials[b] = logz - gold;     // identical value both reps
    }
}

__global__ __launch_bounds__(256) void k_reduce(const float* __restrict__ partials,
                                               float* __restrict__ out)
{
    __shared__ float sh[256];
    const int t = threadIdx.x;
    float s = 0.f;
    #pragma unroll
    for (int j = 0; j < 32; ++j) s += partials[t + 256 * j];
    sh[t] = s;
    __syncthreads();
    #pragma unroll
    for (int d = 128; d > 0; d >>= 1) {
        if (t < d) sh[t] += sh[t + d];
        __syncthreads();
    }
    if (t == 0) out[0] = sh[0] * (1.0f / 8192.0f);
}

extern "C" void kernel_launch(void* const* d_in, const int* in_sizes, int n_in,
                              void* d_out, int out_size, void* d_ws, size_t ws_size,
                              hipStream_t stream) {
    const float* feats = (const float*)d_in[0];
    const float* trans = (const float*)d_in[1];
    const int*   tags  = (const int*)d_in[2];
    const int*   lens  = (const int*)d_in[3];
    float* out = (float*)d_out;
    float* partials = (float*)d_ws;        // 8192 floats

    crf_tree<<<BB / 4, 256, 0, stream>>>(feats, trans, tags, lens, partials);
    k_reduce<<<1, 256, 0, stream>>>(partials, out);
}

// Round 10
// 37.477 us; speedup vs baseline: 1.5312x; 1.5312x over previous
//
#include <hip/hip_runtime.h>

// CRF NLL forward, B=8192, L=512, T=6 (4 real states + START/STOP).
// One wave per batch. Lane l builds the ordered product of M_l for its 8
// contiguous steps (M = diag(exp(feat)) * E, scaled-probability domain,
// power-of-2 renorm, exponent in an int). Combine: 6-round ordered
// __shfl_down reduction (P <- P_{lane+k} * P_lane, no operand selects;
// lane 0 ends with the full 512-step product). Gold fused per-lane and
// shuffle-reduced. 128-thr blocks, launch_bounds(128,8) -> 32 waves/CU
// (R9 found launch_bounds(256,4) had capped occupancy at 50%).

#define BB 8192
#define LL 512
#define LN2F 0.69314718055994530942f

__device__ __forceinline__ float uniformf(float x) {
    return __uint_as_float(__builtin_amdgcn_readfirstlane(__float_as_uint(x)));
}

#define RENORM16(P, MEX)                                                \
  do {                                                                  \
    float m_ = fmaxf(P[0], P[1]);                                       \
    _Pragma("unroll") for (int z_ = 2; z_ < 16; ++z_) m_ = fmaxf(m_, P[z_]); \
    const int ee_ = (int)((__float_as_uint(m_) >> 23) & 255) - 127;     \
    const float sc_ = __uint_as_float((unsigned)(127 - ee_) << 23);     \
    _Pragma("unroll") for (int z_ = 0; z_ < 16; ++z_) P[z_] *= sc_;     \
    MEX += ee_;                                                         \
  } while (0)

// One leaf step for r>=1: P <- diag(exp(f)) * E * P (masked), fused gold.
#define STEP(R, F0, F1, F2, F3)                                         \
  do {                                                                  \
    const bool act_ = (base + (R)) < len;                               \
    const float f0_=(F0), f1_=(F1), f2_=(F2), f3_=(F3);                 \
    const float fe0_=__expf(f0_), fe1_=__expf(f1_);                     \
    const float fe2_=__expf(f2_), fe3_=__expf(f3_);                     \
    _Pragma("unroll")                                                   \
    for (int j = 0; j < 4; ++j) {                                       \
      const float c0_=P[0*4+j], c1_=P[1*4+j], c2_=P[2*4+j], c3_=P[3*4+j]; \
      const float t0_ = fmaf(E[0], c0_, fmaf(E[1], c1_, fmaf(E[2], c2_, E[3] *c3_))); \
      const float t1_ = fmaf(E[4], c0_, fmaf(E[5], c1_, fmaf(E[6], c2_, E[7] *c3_))); \
      const float t2_ = fmaf(E[8], c0_, fmaf(E[9], c1_, fmaf(E[10],c2_, E[11]*c3_))); \
      const float t3_ = fmaf(E[12],c0_, fmaf(E[13],c1_, fmaf(E[14],c2_, E[15]*c3_))); \
      P[0*4+j] = act_ ? fe0_*t0_ : P[0*4+j];                            \
      P[1*4+j] = act_ ? fe1_*t1_ : P[1*4+j];                            \
      P[2*4+j] = act_ ? fe2_*t2_ : P[2*4+j];                            \
      P[3*4+j] = act_ ? fe3_*t3_ : P[3*4+j];                            \
    }                                                                   \
    const int tg_ = tg##R;                                              \
    const float lut_ = sT[tg_ * 6 + tgp##R];                            \
    const float em_  = (tg_ & 2) ? ((tg_ & 1) ? f3_ : f2_)              \
                                 : ((tg_ & 1) ? f1_ : f0_);             \
    gold += act_ ? (lut_ + em_) : 0.f;                                  \
  } while (0)

__global__ __launch_bounds__(128, 8) void crf_tree(
    const float* __restrict__ feats,
    const float* __restrict__ trans,
    const int*   __restrict__ tags,
    const int*   __restrict__ lens,
    float* __restrict__ partials)
{
    __shared__ float sT[36];

    const int tid  = threadIdx.x;
    const int lane = tid & 63;
    const int wv   = tid >> 6;
    const int b    = blockIdx.x * 2 + wv;

    if (tid < 36) sT[tid] = trans[tid];
    __syncthreads();

    // wave-uniform transition constants (SGPR via readfirstlane)
    float E[16], e4[4], e5[4];
    #pragma unroll
    for (int i = 0; i < 16; ++i)
        E[i] = uniformf(__expf(sT[(i >> 2) * 6 + (i & 3)]));
    #pragma unroll
    for (int i = 0; i < 4; ++i) {
        e4[i] = uniformf(__expf(sT[i * 6 + 4]));   // exp(trans[i][START])
        e5[i] = uniformf(__expf(sT[30 + i]));      // exp(trans[STOP][i])
    }

    const int len  = lens[b];
    const int base = lane * 8;
    const bool lane0 = (lane == 0);

    // ---- loads: 4 used emission columns only (128B/lane) ----
    const float* fp = feats + (size_t)b * (LL * 6) + lane * 48;
    const float4 A0 = *(const float4*)(fp + 0);    // step 0: f0..f3
    const float2 A1 = *(const float2*)(fp + 6);    // step 1: f0,f1
    const float2 A2 = *(const float2*)(fp + 8);    // step 1: f2,f3
    const float4 B0 = *(const float4*)(fp + 12);   // step 2
    const float2 B1 = *(const float2*)(fp + 18);   // step 3
    const float2 B2 = *(const float2*)(fp + 20);
    const float4 C0 = *(const float4*)(fp + 24);   // step 4
    const float2 C1 = *(const float2*)(fp + 30);   // step 5
    const float2 C2 = *(const float2*)(fp + 32);
    const float4 D0 = *(const float4*)(fp + 36);   // step 6
    const float2 D1 = *(const float2*)(fp + 42);   // step 7
    const float2 D2 = *(const float2*)(fp + 44);

    const int* tbp = tags + (size_t)b * LL + base;
    const int4 ta  = *(const int4*)tbp;
    const int4 tb4 = *(const int4*)(tbp + 4);
    const int tg0=ta.x&3,  tg1=ta.y&3,  tg2=ta.z&3,  tg3=ta.w&3;
    const int tg4=tb4.x&3, tg5=tb4.y&3, tg6=tb4.z&3, tg7=tb4.w&3;
    const int ptail = __shfl_up(tg7, 1, 64);
    const int prev0 = lane0 ? 4 : ptail;
    const int tgp1=tg0, tgp2=tg1, tgp3=tg2,
              tgp4=tg3, tgp5=tg4, tgp6=tg5, tgp7=tg6;   // prev-tag per step

    float P[16];
    #pragma unroll
    for (int z = 0; z < 16; ++z) P[z] = (z % 5 == 0) ? 1.f : 0.f;
    int   mex  = 0;
    float gold = 0.f;

    // ---- step 0 specialized: P = diag(fe) * (lane0 ? e4-cols : E) ----
    {
        const bool act_ = base < len;
        const float f0_=A0.x, f1_=A0.y, f2_=A0.z, f3_=A0.w;
        const float fe0_=__expf(f0_), fe1_=__expf(f1_);
        const float fe2_=__expf(f2_), fe3_=__expf(f3_);
        #pragma unroll
        for (int j = 0; j < 4; ++j) {
            const float t0_ = lane0 ? e4[0] : E[0*4+j];
            const float t1_ = lane0 ? e4[1] : E[1*4+j];
            const float t2_ = lane0 ? e4[2] : E[2*4+j];
            const float t3_ = lane0 ? e4[3] : E[3*4+j];
            P[0*4+j] = act_ ? fe0_*t0_ : P[0*4+j];
            P[1*4+j] = act_ ? fe1_*t1_ : P[1*4+j];
            P[2*4+j] = act_ ? fe2_*t2_ : P[2*4+j];
            P[3*4+j] = act_ ? fe3_*t3_ : P[3*4+j];
        }
        const float lut_ = sT[tg0 * 6 + prev0];
        const float em_  = (tg0 & 2) ? ((tg0 & 1) ? f3_ : f2_)
                                     : ((tg0 & 1) ? f1_ : f0_);
        gold += act_ ? (lut_ + em_) : 0.f;
    }
    STEP(1, A1.x, A1.y, A2.x, A2.y);
    STEP(2, B0.x, B0.y, B0.z, B0.w);
    STEP(3, B1.x, B1.y, B2.x, B2.y);
    RENORM16(P, mex);
    STEP(4, C0.x, C0.y, C0.z, C0.w);
    STEP(5, C1.x, C1.y, C2.x, C2.y);
    STEP(6, D0.x, D0.y, D0.z, D0.w);
    STEP(7, D1.x, D1.y, D2.x, D2.y);
    RENORM16(P, mex);

    // terminal gold: lane owning step len-1 adds trans[STOP][last_tag]
    {
        const unsigned dl = (unsigned)(len - 1 - base);
        if (dl < 8u) gold += sT[30 + (tbp[dl] & 3)];
    }

    // ---- ordered shfl_down reduction: lane 0 ends with P_63 ... P_0 ----
    // No operand selects: every lane computes Q*P (Q = later segment from
    // lane+k). High lanes hold garbage products of positive entries
    // (harmless); lane 0's chain is exact. Renorm only while deep products
    // still accumulate (k<=8); entries stay <= ~1024 after that (safe).
    #pragma unroll
    for (int k = 1; k <= 32; k <<= 1) {
        float Q[16];
        #pragma unroll
        for (int z = 0; z < 16; ++z) Q[z] = __shfl_down(P[z], k, 64);
        const int mq = __shfl_down(mex, k, 64);
        float N[16];
        #pragma unroll
        for (int i = 0; i < 4; ++i)
            #pragma unroll
            for (int j = 0; j < 4; ++j)
                N[i*4+j] = fmaf(Q[i*4+0], P[0*4+j], fmaf(Q[i*4+1], P[1*4+j],
                           fmaf(Q[i*4+2], P[2*4+j], Q[i*4+3] * P[3*4+j])));
        #pragma unroll
        for (int z = 0; z < 16; ++z) P[z] = N[z];
        mex += mq;
        if (k <= 8) RENORM16(P, mex);
    }

    // gold: sum across lanes
    #pragma unroll
    for (int k = 1; k <= 32; k <<= 1)
        gold += __shfl_xor(gold, k, 64);

    // lane 0: columns of P all equal alpha (e4 folded into lane 0's leaf)
    const float dot = fmaf(e5[0], P[0], fmaf(e5[1], P[4],
                      fmaf(e5[2], P[8], e5[3] * P[12])));
    const float logz = fmaf((float)mex, LN2F, __logf(dot));
    if (lane == 0)
        partials[b] = logz - gold;
}

__global__ __launch_bounds__(256) void k_reduce(const float* __restrict__ partials,
                                               float* __restrict__ out)
{
    __shared__ float sh[256];
    const int t = threadIdx.x;
    float s = 0.f;
    #pragma unroll
    for (int j = 0; j < 32; ++j) s += partials[t + 256 * j];
    sh[t] = s;
    __syncthreads();
    #pragma unroll
    for (int d = 128; d > 0; d >>= 1) {
        if (t < d) sh[t] += sh[t + d];
        __syncthreads();
    }
    if (t == 0) out[0] = sh[0] * (1.0f / 8192.0f);
}

extern "C" void kernel_launch(void* const* d_in, const int* in_sizes, int n_in,
                              void* d_out, int out_size, void* d_ws, size_t ws_size,
                              hipStream_t stream) {
    const float* feats = (const float*)d_in[0];
    const float* trans = (const float*)d_in[1];
    const int*   tags  = (const int*)d_in[2];
    const int*   lens  = (const int*)d_in[3];
    float* out = (float*)d_out;
    float* partials = (float*)d_ws;        // 8192 floats

    crf_tree<<<BB / 2, 128, 0, stream>>>(feats, trans, tags, lens, partials);
    k_reduce<<<1, 256, 0, stream>>>(partials, out);
}